// Round 7
// baseline (194.690 us; speedup 1.0000x reference)
//
#include <hip/hip_runtime.h>

// LTC cell: B=1024, I=128, N=256, 6 unfolds. Round 7.
// Round-6 fused structure (bb=2, grid 512, 2 blocks/CU, 8 waves/SIMD) with
// i-PAIR packing to amortize per-iteration overhead:
//  - weights: f16x8 {A0,B0,W0,E0, A1,B1,W1,E1} = 16 B per (i-pair, n)
//    -> ONE dwordx4 per 2 i (was 2 dwordx2), half the address math
//  - v tile: float4 {v(2j,b0), v(2j,b1), v(2j+1,b0), v(2j+1,b1)}
//    -> ONE ds_read_b128 broadcast per 2 i (was 2 ds_read_b64)
//  - 4 independent sigmoid chains per loop body (trans-latency overlap)
// A = -sigma*log2e, B = sigma*mu*log2e; sigmoid = 1/(1+exp2(fma(A,v,B))).

#define LOG2E 1.44269504088896340f

constexpr int Bn = 1024;
constexpr int In = 128;
constexpr int Nn = 256;
constexpr int UNFOLDS = 6;

typedef _Float16 h8 __attribute__((ext_vector_type(8)));

#if __has_builtin(__builtin_amdgcn_exp2f)
#define EXP2F(x) __builtin_amdgcn_exp2f(x)
#else
#define EXP2F(x) __exp2f(x)
#endif
#if __has_builtin(__builtin_amdgcn_rcpf)
#define RCPF(x) __builtin_amdgcn_rcpf(x)
#else
#define RCPF(x) (1.0f / (x))
#endif

// ---------------------------------------------------------------------------
// Pack: PrecH2[j*N+n] = f16x8 for i-pair (2j, 2j+1) at column n.
// ---------------------------------------------------------------------------
__global__ __launch_bounds__(256) void pack_kernel(
    const float* __restrict__ mu, const float* __restrict__ sigma,
    const float* __restrict__ W, const float* __restrict__ erev,
    const float* __restrict__ smu, const float* __restrict__ ssigma,
    const float* __restrict__ sW, const float* __restrict__ serev,
    h8* __restrict__ PrecH2, h8* __restrict__ PsenH2) {
    int idx = blockIdx.x * 256 + threadIdx.x;
    if (idx < 128 * Nn) {  // recurrent: j = idx>>8 in [0,128), n = idx&255
        int n = idx & 255, j = idx >> 8;
        int a = (2 * j) * Nn + n, b = a + Nn;
        float s0 = sigma[a], m0 = mu[a], w0 = W[a];
        float s1 = sigma[b], m1 = mu[b], w1 = W[b];
        h8 h;
        h[0] = (_Float16)(-s0 * LOG2E);
        h[1] = (_Float16)(s0 * m0 * LOG2E);
        h[2] = (_Float16)w0;
        h[3] = (_Float16)(w0 * erev[a]);
        h[4] = (_Float16)(-s1 * LOG2E);
        h[5] = (_Float16)(s1 * m1 * LOG2E);
        h[6] = (_Float16)w1;
        h[7] = (_Float16)(w1 * erev[b]);
        PrecH2[idx] = h;
        return;
    }
    int jdx = idx - 128 * Nn;
    if (jdx < 64 * Nn) {   // sensory: j = jdx>>8 in [0,64), n = jdx&255
        int n = jdx & 255, j = jdx >> 8;
        int a = (2 * j) * Nn + n, b = a + Nn;
        float s0 = ssigma[a], m0 = smu[a], w0 = sW[a];
        float s1 = ssigma[b], m1 = smu[b], w1 = sW[b];
        h8 h;
        h[0] = (_Float16)(-s0 * LOG2E);
        h[1] = (_Float16)(s0 * m0 * LOG2E);
        h[2] = (_Float16)w0;
        h[3] = (_Float16)(w0 * serev[a]);
        h[4] = (_Float16)(-s1 * LOG2E);
        h[5] = (_Float16)(s1 * m1 * LOG2E);
        h[6] = (_Float16)w1;
        h[7] = (_Float16)(w1 * serev[b]);
        PsenH2[jdx] = h;
    }
}

// 4 sigmoid terms from one h8 + one float4 (2 i x 2 batches).
#define PAIR4(hw, v4)                                                     \
    {                                                                     \
        float t00 = fmaf((float)(hw)[0], (v4).x, (float)(hw)[1]);         \
        float t01 = fmaf((float)(hw)[0], (v4).y, (float)(hw)[1]);         \
        float t10 = fmaf((float)(hw)[4], (v4).z, (float)(hw)[5]);         \
        float t11 = fmaf((float)(hw)[4], (v4).w, (float)(hw)[5]);         \
        float e00 = EXP2F(t00), e01 = EXP2F(t01);                         \
        float e10 = EXP2F(t10), e11 = EXP2F(t11);                         \
        float r00 = RCPF(1.f + e00), r01 = RCPF(1.f + e01);               \
        float r10 = RCPF(1.f + e10), r11 = RCPF(1.f + e11);               \
        den0 = fmaf((float)(hw)[2], r00, den0);                           \
        den1 = fmaf((float)(hw)[2], r01, den1);                           \
        num0 = fmaf((float)(hw)[3], r00, num0);                           \
        num1 = fmaf((float)(hw)[3], r01, num1);                           \
        den0 = fmaf((float)(hw)[6], r10, den0);                           \
        den1 = fmaf((float)(hw)[6], r11, den1);                           \
        num0 = fmaf((float)(hw)[7], r10, num0);                           \
        num1 = fmaf((float)(hw)[7], r11, num1);                           \
    }

// ---------------------------------------------------------------------------
// Fused LTC kernel: sensory + 6 unfolds. Grid 512 x 1024 thr.
// Block owns 2 batches x all 256 n. thread = (n = tid&255, ih = tid>>8).
// ---------------------------------------------------------------------------
__global__ __launch_bounds__(1024, 8) void ltc_fused_kernel(
    const float* __restrict__ inputs, const float* __restrict__ state,
    const float* __restrict__ input_w, const float* __restrict__ input_b,
    const h8* __restrict__ PsenH2, const h8* __restrict__ PrecH2,
    const float* __restrict__ vleak, const float* __restrict__ gleak,
    const float* __restrict__ cmt, float* __restrict__ out) {
    __shared__ float4 vt4[Nn / 2];       // [j] = {v2j_b0, v2j_b1, v2j1_b0, v2j1_b1}, 2 KB
    __shared__ float4 xs4[In / 2];       // same for sensory x, 1 KB
    __shared__ float2 part[4][2][Nn];    // [ih][bb][n], 16 KB

    const int tid = threadIdx.x;
    const int b0 = blockIdx.x * 2;
    const int n = tid & 255;
    const int ih = tid >> 8;

    float vp = 0.f, g = 0.f, c = 0.f, gvl = 0.f;
    if (ih < 2) {
        vp = state[(b0 + ih) * Nn + n];   // coalesced
        ((float*)vt4)[(n >> 1) * 4 + (n & 1) * 2 + ih] = vp;
        g = gleak[n];
        c = cmt[n];
        gvl = g * vleak[n];
    }
    if (tid < 256) {                      // xs: 128 i x 2 bb
        int i = tid & 127, bb = tid >> 7;
        ((float*)xs4)[(i >> 1) * 4 + (i & 1) * 2 + bb] =
            inputs[(b0 + bb) * In + i] * input_w[i] + input_b[i];
    }
    __syncthreads();

    // ---- sensory: 16 i-pairs per ih ----
    float sens_n = 0.f, sens_d = 0.f;
    {
        float num0 = 0.f, num1 = 0.f, den0 = 0.f, den1 = 0.f;
        const h8* __restrict__ p = PsenH2 + n;
        const int j0 = ih * 16;
#pragma unroll 8
        for (int j = j0; j < j0 + 16; ++j) {
            h8 hw = p[j * Nn];   // coalesced dwordx4
            float4 v4 = xs4[j];  // ds_read_b128 broadcast
            PAIR4(hw, v4);
        }
        part[ih][0][n] = make_float2(num0, den0);
        part[ih][1][n] = make_float2(num1, den1);
        __syncthreads();
        if (ih < 2) {
#pragma unroll
            for (int s = 0; s < 4; ++s) {
                float2 v = part[s][ih][n];
                sens_n += v.x;
                sens_d += v.y;
            }
        }
    }

    // ---- 6 unfolds: 32 i-pairs per ih ----
    const h8* __restrict__ p = PrecH2 + n;
    for (int s = 0; s < UNFOLDS; ++s) {
        __syncthreads();  // vt4 updated & part free
        float num0 = 0.f, num1 = 0.f, den0 = 0.f, den1 = 0.f;
        const int j0 = ih * 32;
#pragma unroll 8
        for (int j = j0; j < j0 + 32; ++j) {
            h8 hw = p[j * Nn];   // coalesced dwordx4 (L2-resident stream)
            float4 v4 = vt4[j];  // ds_read_b128 broadcast
            PAIR4(hw, v4);
        }
        part[ih][0][n] = make_float2(num0, den0);
        part[ih][1][n] = make_float2(num1, den1);
        __syncthreads();
        if (ih < 2) {
            float wn = sens_n, wd = sens_d;
#pragma unroll
            for (int s2 = 0; s2 < 4; ++s2) {
                float2 v = part[s2][ih][n];
                wn += v.x;
                wd += v.y;
            }
            float res = (fmaf(c, vp, gvl) + wn) * RCPF(c + g + wd);
            vp = res;
            if (s == UNFOLDS - 1)
                out[(b0 + ih) * Nn + n] = res;   // coalesced
            else
                ((float*)vt4)[(n >> 1) * 4 + (n & 1) * 2 + ih] = res;
        }
    }
}

// ---------------------------------------------------------------------------
extern "C" void kernel_launch(void* const* d_in, const int* in_sizes, int n_in,
                              void* d_out, int out_size, void* d_ws, size_t ws_size,
                              hipStream_t stream) {
    const float* inputs   = (const float*)d_in[0];
    const float* state    = (const float*)d_in[1];
    const float* input_w  = (const float*)d_in[2];
    const float* input_b  = (const float*)d_in[3];
    const float* smu      = (const float*)d_in[4];
    const float* ssigma   = (const float*)d_in[5];
    const float* sW       = (const float*)d_in[6];
    const float* serev    = (const float*)d_in[7];
    const float* mu       = (const float*)d_in[8];
    const float* sigma    = (const float*)d_in[9];
    const float* W        = (const float*)d_in[10];
    const float* erev     = (const float*)d_in[11];
    const float* vleak    = (const float*)d_in[12];
    const float* gleak    = (const float*)d_in[13];
    const float* cmt      = (const float*)d_in[14];
    float* out = (float*)d_out;

    // Workspace: PrecH2 512 KiB | PsenH2 256 KiB
    char* ws = (char*)d_ws;
    h8* PrecH2 = (h8*)ws;
    h8* PsenH2 = (h8*)(ws + (512u << 10));

    pack_kernel<<<(128 * Nn + 64 * Nn + 255) / 256, 256, 0, stream>>>(
        mu, sigma, W, erev, smu, ssigma, sW, serev, PrecH2, PsenH2);

    ltc_fused_kernel<<<Bn / 2, 1024, 0, stream>>>(
        inputs, state, input_w, input_b, PsenH2, PrecH2, vleak, gleak, cmt, out);
}

// Round 8
// 191.469 us; speedup vs baseline: 1.0168x; 1.0168x over previous
//
#include <hip/hip_runtime.h>

// LTC cell: B=1024, I=128, N=256, 6 unfolds. Round 8.
// Round-6 shape (1024 thr, bb=2, grid 512 -> 2 blocks/CU, 8 waves/SIMD) with
// the f16 conversion tax removed: weights stay packed f16x4 = 8 B/(i,n)
// {A=-sig*log2e (lo), B=sig*mu*log2e (hi) | W (lo), E=W*erev (hi)} but are
// consumed via explicit inline-asm v_fma_mix_f32 (f16 halves selected with
// op_sel, f32 accumulate) -> no v_cvt_f32_f16 / v_lshrrev in the hot loop.
// Per i-iter (2 terms): 2 mix-fma + 2 exp2 + 2 add + 2 rcp + 4 mix-fma
// + 1 global dwordx2 + 1 ds_read_b64. sigmoid = 1/(1+exp2(A*v+B)).

#define LOG2E 1.44269504088896340f

constexpr int Bn = 1024;
constexpr int In = 128;
constexpr int Nn = 256;
constexpr int UNFOLDS = 6;

#if __has_builtin(__builtin_amdgcn_exp2f)
#define EXP2F(x) __builtin_amdgcn_exp2f(x)
#else
#define EXP2F(x) __exp2f(x)
#endif
#if __has_builtin(__builtin_amdgcn_rcpf)
#define RCPF(x) __builtin_amdgcn_rcpf(x)
#else
#define RCPF(x) (1.0f / (x))
#endif

__device__ __forceinline__ unsigned pack2h(float lo, float hi) {
    _Float16 hl = (_Float16)lo, hh = (_Float16)hi;
    union { _Float16 h; unsigned short u; } a, b;
    a.h = hl;
    b.h = hh;
    return (unsigned)a.u | ((unsigned)b.u << 16);
}

// ---------------------------------------------------------------------------
// Pack: PrecU[i*N+n] = uint2 { B<<16 | A , E<<16 | W } (all f16 bits)
// A = -sigma*log2e, B = sigma*mu*log2e, E = W*erev. Same for PsenU.
// ---------------------------------------------------------------------------
__global__ __launch_bounds__(256) void pack_kernel(
    const float* __restrict__ mu, const float* __restrict__ sigma,
    const float* __restrict__ W, const float* __restrict__ erev,
    const float* __restrict__ smu, const float* __restrict__ ssigma,
    const float* __restrict__ sW, const float* __restrict__ serev,
    uint2* __restrict__ PrecU, uint2* __restrict__ PsenU) {
    int idx = blockIdx.x * 256 + threadIdx.x;
    if (idx < Nn * Nn) {
        float s = sigma[idx], m = mu[idx], w = W[idx], e = erev[idx];
        PrecU[idx] = make_uint2(pack2h(-s * LOG2E, s * m * LOG2E),
                                pack2h(w, w * e));
        return;
    }
    int j = idx - Nn * Nn;
    if (j < In * Nn) {
        float s = ssigma[j], m = smu[j], w = sW[j], e = serev[j];
        PsenU[j] = make_uint2(pack2h(-s * LOG2E, s * m * LOG2E),
                              pack2h(w, w * e));
    }
}

// Two sigmoid terms (one i, 2 batches) via v_fma_mix_f32 (no cvts).
// hw.x = B<<16|A (f16), hw.y = E<<16|W (f16); vx,vy = f32 v for 2 batches.
#define SIG2(hw, vx, vy)                                                      \
    {                                                                         \
        float t0, t1;                                                         \
        asm("v_fma_mix_f32 %0, %1, %2, %1 op_sel:[0,0,1] op_sel_hi:[1,0,1]"   \
            : "=v"(t0) : "v"((hw).x), "v"(vx));                               \
        asm("v_fma_mix_f32 %0, %1, %2, %1 op_sel:[0,0,1] op_sel_hi:[1,0,1]"   \
            : "=v"(t1) : "v"((hw).x), "v"(vy));                               \
        float r0 = RCPF(1.f + EXP2F(t0));                                     \
        float r1 = RCPF(1.f + EXP2F(t1));                                     \
        asm("v_fma_mix_f32 %0, %1, %2, %0 op_sel:[0,0,0] op_sel_hi:[1,0,0]"   \
            : "+v"(den0) : "v"((hw).y), "v"(r0));                             \
        asm("v_fma_mix_f32 %0, %1, %2, %0 op_sel:[0,0,0] op_sel_hi:[1,0,0]"   \
            : "+v"(den1) : "v"((hw).y), "v"(r1));                             \
        asm("v_fma_mix_f32 %0, %1, %2, %0 op_sel:[1,0,0] op_sel_hi:[1,0,0]"   \
            : "+v"(num0) : "v"((hw).y), "v"(r0));                             \
        asm("v_fma_mix_f32 %0, %1, %2, %0 op_sel:[1,0,0] op_sel_hi:[1,0,0]"   \
            : "+v"(num1) : "v"((hw).y), "v"(r1));                             \
    }

// ---------------------------------------------------------------------------
// Fused LTC kernel: sensory + 6 unfolds.
// Grid 512 x 1024 thr. Block owns 2 batches x all 256 n.
// thread = (n = tid&255, ih = tid>>8 in 0..3); ih = i-slice; ih<2 also owns
// the (bb=ih, n) output.
// ---------------------------------------------------------------------------
__global__ __launch_bounds__(1024, 8) void ltc_fused_kernel(
    const float* __restrict__ inputs, const float* __restrict__ state,
    const float* __restrict__ input_w, const float* __restrict__ input_b,
    const uint2* __restrict__ PsenU, const uint2* __restrict__ PrecU,
    const float* __restrict__ vleak, const float* __restrict__ gleak,
    const float* __restrict__ cmt, float* __restrict__ out) {
    __shared__ float2 vt[Nn];            // [i] -> 2 batches, 2 KB
    __shared__ float2 xs[In];            // [i] -> 2 batches, 1 KB
    __shared__ float2 part[4][2][Nn];    // [ih][bb][n], 16 KB

    const int tid = threadIdx.x;
    const int b0 = blockIdx.x * 2;
    const int n = tid & 255;
    const int ih = tid >> 8;

    float vp = 0.f, g = 0.f, c = 0.f, gvl = 0.f;
    if (ih < 2) {
        vp = state[(b0 + ih) * Nn + n];        // coalesced
        ((float*)vt)[n * 2 + ih] = vp;
        g = gleak[n];
        c = cmt[n];
        gvl = g * vleak[n];
    }
    if (tid < 256) {                           // xs: 128 i x 2 bb
        int i = tid & 127, bb = tid >> 7;
        ((float*)xs)[i * 2 + bb] =
            inputs[(b0 + bb) * In + i] * input_w[i] + input_b[i];
    }
    __syncthreads();

    // ---- sensory: slice of 32 i per ih ----
    float sens_n = 0.f, sens_d = 0.f;
    {
        float num0 = 0.f, num1 = 0.f, den0 = 0.f, den1 = 0.f;
        const uint2* __restrict__ p = PsenU + n;
        const int j0 = ih * 32;
#pragma unroll 8
        for (int i = j0; i < j0 + 32; ++i) {
            uint2 hw = p[i * Nn];    // coalesced dwordx2
            float2 v2 = xs[i];       // ds_read_b64 broadcast
            SIG2(hw, v2.x, v2.y);
        }
        part[ih][0][n] = make_float2(num0, den0);
        part[ih][1][n] = make_float2(num1, den1);
        __syncthreads();
        if (ih < 2) {
#pragma unroll
            for (int s = 0; s < 4; ++s) {
                float2 v = part[s][ih][n];
                sens_n += v.x;
                sens_d += v.y;
            }
        }
    }

    // ---- 6 unfolds: slice of 64 i per ih ----
    const uint2* __restrict__ p = PrecU + n;
    for (int s = 0; s < UNFOLDS; ++s) {
        __syncthreads();  // vt updated & part free for reuse
        float num0 = 0.f, num1 = 0.f, den0 = 0.f, den1 = 0.f;
        const int j0 = ih * 64;
#pragma unroll 8
        for (int i = j0; i < j0 + 64; ++i) {
            uint2 hw = p[i * Nn];    // coalesced dwordx2 (L2-resident stream)
            float2 v2 = vt[i];       // ds_read_b64 broadcast
            SIG2(hw, v2.x, v2.y);
        }
        part[ih][0][n] = make_float2(num0, den0);
        part[ih][1][n] = make_float2(num1, den1);
        __syncthreads();
        if (ih < 2) {
            float wn = sens_n, wd = sens_d;
#pragma unroll
            for (int s2 = 0; s2 < 4; ++s2) {
                float2 v = part[s2][ih][n];
                wn += v.x;
                wd += v.y;
            }
            float res = (fmaf(c, vp, gvl) + wn) * RCPF(c + g + wd);
            vp = res;
            if (s == UNFOLDS - 1)
                out[(b0 + ih) * Nn + n] = res;   // coalesced
            else
                ((float*)vt)[n * 2 + ih] = res;
        }
    }
}

// ---------------------------------------------------------------------------
extern "C" void kernel_launch(void* const* d_in, const int* in_sizes, int n_in,
                              void* d_out, int out_size, void* d_ws, size_t ws_size,
                              hipStream_t stream) {
    const float* inputs   = (const float*)d_in[0];
    const float* state    = (const float*)d_in[1];
    const float* input_w  = (const float*)d_in[2];
    const float* input_b  = (const float*)d_in[3];
    const float* smu      = (const float*)d_in[4];
    const float* ssigma   = (const float*)d_in[5];
    const float* sW       = (const float*)d_in[6];
    const float* serev    = (const float*)d_in[7];
    const float* mu       = (const float*)d_in[8];
    const float* sigma    = (const float*)d_in[9];
    const float* W        = (const float*)d_in[10];
    const float* erev     = (const float*)d_in[11];
    const float* vleak    = (const float*)d_in[12];
    const float* gleak    = (const float*)d_in[13];
    const float* cmt      = (const float*)d_in[14];
    float* out = (float*)d_out;

    // Workspace: PrecU 512 KiB | PsenU 256 KiB
    char* ws = (char*)d_ws;
    uint2* PrecU = (uint2*)ws;
    uint2* PsenU = (uint2*)(ws + (512u << 10));

    pack_kernel<<<(Nn * Nn + In * Nn + 255) / 256, 256, 0, stream>>>(
        mu, sigma, W, erev, smu, ssigma, sW, serev, PrecU, PsenU);

    ltc_fused_kernel<<<Bn / 2, 1024, 0, stream>>>(
        inputs, state, input_w, input_b, PsenU, PrecU, vleak, gleak, cmt, out);
}